// Round 4
// baseline (1731.161 us; speedup 1.0000x reference)
//
#include <hip/hip_runtime.h>
#include <hip/hip_bf16.h>

// Problem constants: N=64, C=64, T=128, V=25, H=3, DQ=32
// Inputs: float32. Output: float32 (compared under bf16-floored threshold).

#define WS_ATT   0         // 120000 floats: final att[n,h,u,v]
#define WS_STATS 120000    // 128 floats: per-channel sum, sumsq

// ---------------------------------------------------------------------------
// K1: att[n,h,u,v] = tanh( (sum_{c',t} q*k) / 4096 ) * alpha[h] + att0[h,u,v]
// One block per (h, n); loops T in chunks of 2 frames. No atomics.
// ---------------------------------------------------------------------------
__global__ __launch_bounds__(256) void k_att(
    const float* __restrict__ x, const float* __restrict__ Wqkv,
    const float* __restrict__ bqkv, const float* __restrict__ alphas,
    const float* __restrict__ att0s, float* __restrict__ att_out)
{
    __shared__ float wq_s[2048], wk_s[2048];   // [c'(32)][c(64)]
    __shared__ float bq_s[32], bk_s[32];
    __shared__ float pe_s[1600];               // [c][v]
    __shared__ float xs_s[3200];               // [c][j], j = tl*25+v, 2 frames
    __shared__ float q_s[1600], k_s[1600];     // [c'][j]

    const int tid = threadIdx.x;
    const int h = blockIdx.x, n = blockIdx.y;

    for (int e = tid; e < 2048; e += 256) {
        int cp = e >> 6, c = e & 63;
        wq_s[e] = Wqkv[(h * 32 + cp) * 64 + c];
        wk_s[e] = Wqkv[(96 + h * 32 + cp) * 64 + c];
    }
    if (tid < 32) {
        bq_s[tid] = bqkv[h * 32 + tid];
        bk_s[tid] = bqkv[96 + h * 32 + tid];
    }
    for (int e = tid; e < 1600; e += 256) {
        int c = e / 25, v = e % 25;
        int i = c >> 1;
        float d = expf(-(float)(2 * i) * (9.210340371976184f / 64.0f));
        float a = (float)v * d;
        pe_s[e] = (c & 1) ? cosf(a) : sinf(a);
    }

    float racc[3] = {0.0f, 0.0f, 0.0f};   // owns p = tid, tid+256, tid+512

    for (int chunk = 0; chunk < 64; ++chunk) {
        const int t0 = chunk * 2;
        __syncthreads();   // protect xs_s / q_s / k_s from previous readers
        for (int e = tid; e < 3200; e += 256) {
            int c = e / 50, j = e % 50;
            int tl = j / 25, v = j % 25;
            xs_s[e] = x[((n * 64 + c) * 128 + t0 + tl) * 25 + v] + pe_s[c * 25 + v];
        }
        __syncthreads();
        for (int e = tid; e < 1600; e += 256) {
            int row = e / 50, j = e % 50;
            float aq = bq_s[row], ak = bk_s[row];
            const float* wqr = &wq_s[row * 64];
            const float* wkr = &wk_s[row * 64];
            #pragma unroll 8
            for (int c = 0; c < 64; ++c) {
                float xv = xs_s[c * 50 + j];
                aq = fmaf(wqr[c], xv, aq);
                ak = fmaf(wkr[c], xv, ak);
            }
            q_s[e] = aq; k_s[e] = ak;
        }
        __syncthreads();
        #pragma unroll
        for (int s = 0; s < 3; ++s) {
            int p = tid + s * 256;
            if (p < 625) {
                int u = p / 25, v = p % 25;
                float acc = racc[s];
                for (int cp = 0; cp < 32; ++cp) {
                    const float* qr = &q_s[cp * 50];
                    const float* kr = &k_s[cp * 50];
                    acc = fmaf(qr[u],      kr[v],      acc);
                    acc = fmaf(qr[25 + u], kr[25 + v], acc);
                }
                racc[s] = acc;
            }
        }
    }

    const float alpha = alphas[h];
    #pragma unroll
    for (int s = 0; s < 3; ++s) {
        int p = tid + s * 256;
        if (p < 625) {
            float att = tanhf(racc[s] * (1.0f / 4096.0f)) * alpha + att0s[h * 625 + p];
            att_out[(n * 3 + h) * 625 + p] = att;
        }
    }
}

// ---------------------------------------------------------------------------
// K2: fused y = x . att  and  conv1x5 (+bias) -> fp32 into d_out (staging).
// grid (T/4=32, N=64); 256 threads; thread = (o=tid>>2, tl=tid&3).
// ---------------------------------------------------------------------------
__global__ __launch_bounds__(256) void k_conv(
    const float* __restrict__ x, const float* __restrict__ Wout,
    const float* __restrict__ bout, const float* __restrict__ att,
    float* __restrict__ out)
{
    __shared__ float x_s[6400];    // [c][t(4)*25+v]
    __shared__ float y_s[7424];    // [c][t][vv(29)] zero-padded halo
    __shared__ float att_s[625];

    const int tid = threadIdx.x;
    const int n = blockIdx.y;
    const int t0 = blockIdx.x * 4;
    const int o = tid >> 2, tl = tid & 3;

    for (int e = tid; e < 6400; e += 256) {
        int c = e / 100, r = e % 100;
        int t = r / 25, v = r % 25;
        x_s[e] = x[((n * 64 + c) * 128 + t0 + t) * 25 + v];   // raw x (no pe)
    }
    float acc[25];
    #pragma unroll
    for (int v = 0; v < 25; ++v) acc[v] = 0.0f;

    const float* attw = att + n * 3 * 625;
    for (int h = 0; h < 3; ++h) {
        __syncthreads();           // x_s ready (h=0) / previous y_s,att_s consumed
        for (int e = tid; e < 625; e += 256) att_s[e] = attw[h * 625 + e];
        __syncthreads();
        for (int e = tid; e < 7424; e += 256) {
            int c = e / 116, r = e % 116;
            int t = r / 29, vv = r % 29;
            float s = 0.0f;
            if (vv >= 2 && vv < 27) {
                int v = vv - 2;
                const float* xr = &x_s[c * 100 + t * 25];
                #pragma unroll
                for (int u = 0; u < 25; ++u) s = fmaf(xr[u], att_s[u * 25 + v], s);
            }
            y_s[e] = s;
        }
        __syncthreads();
        for (int c = 0; c < 64; ++c) {
            float yr[29];
            const float* ysrc = &y_s[c * 116 + tl * 29];
            #pragma unroll
            for (int i = 0; i < 29; ++i) yr[i] = ysrc[i];
            const float* wp = &Wout[(size_t)((o * 192) + h * 64 + c) * 5];
            float w0 = wp[0], w1 = wp[1], w2 = wp[2], w3 = wp[3], w4 = wp[4];
            #pragma unroll
            for (int v = 0; v < 25; ++v)
                acc[v] += w0 * yr[v] + w1 * yr[v + 1] + w2 * yr[v + 2]
                        + w3 * yr[v + 3] + w4 * yr[v + 4];
        }
    }
    const float bo = bout[o];
    float* outp = out + ((size_t)(n * 64 + o) * 128 + t0 + tl) * 25;
    #pragma unroll
    for (int v = 0; v < 25; ++v) outp[v] = acc[v] + bo;
}

// ---------------------------------------------------------------------------
// K3: per-channel sum/sumsq of conv output (fp32, staged in d_out).
// One block per channel; direct write (no memset needed).
// ---------------------------------------------------------------------------
__global__ __launch_bounds__(256) void k_stats(const float* __restrict__ conv,
                                               float* __restrict__ stats)
{
    const int o = blockIdx.x;
    const int tid = threadIdx.x;
    float s1 = 0.0f, s2 = 0.0f;
    for (int e = tid; e < 64 * 3200; e += 256) {
        int nn = e / 3200, i = e % 3200;
        float v = conv[(size_t)(nn * 64 + o) * 3200 + i];
        s1 += v; s2 = fmaf(v, v, s2);
    }
    for (int off = 32; off > 0; off >>= 1) {
        s1 += __shfl_down(s1, off);
        s2 += __shfl_down(s2, off);
    }
    __shared__ float r1[4], r2[4];
    int w = tid >> 6;
    if ((tid & 63) == 0) { r1[w] = s1; r2[w] = s2; }
    __syncthreads();
    if (tid == 0) {
        stats[o]      = r1[0] + r1[1] + r1[2] + r1[3];
        stats[64 + o] = r2[0] + r2[1] + r2[2] + r2[3];
    }
}

// ---------------------------------------------------------------------------
// K4: out = leaky_relu( BN(conv) + x ), in place over d_out (1 thread/elem).
// ---------------------------------------------------------------------------
__global__ void k_final(const float* __restrict__ stats, const float* __restrict__ x,
                        const float* __restrict__ gamma, const float* __restrict__ beta,
                        float* __restrict__ out)
{
    size_t idx = (size_t)blockIdx.x * 256 + threadIdx.x;
    if (idx >= (size_t)13107200) return;
    int o = (int)((idx / 3200) & 63);
    const float inv = 1.0f / 204800.0f;
    float m   = stats[o] * inv;
    float ex2 = stats[64 + o] * inv;
    float var = ex2 - m * m;
    float r = rsqrtf(var + 1e-5f);
    float v = out[idx];
    float val = (v - m) * r * gamma[o] + beta[o] + x[idx];
    val = fmaxf(val, 0.1f * val);
    out[idx] = val;
}

// ---------------------------------------------------------------------------
extern "C" void kernel_launch(void* const* d_in, const int* in_sizes, int n_in,
                              void* d_out, int out_size, void* d_ws, size_t ws_size,
                              hipStream_t stream)
{
    const float* x      = (const float*)d_in[0];
    const float* Wqkv   = (const float*)d_in[1];
    const float* bqkv   = (const float*)d_in[2];
    const float* alphas = (const float*)d_in[3];
    const float* att0s  = (const float*)d_in[4];
    const float* Wout   = (const float*)d_in[5];
    const float* bout   = (const float*)d_in[6];
    const float* gamma  = (const float*)d_in[7];
    const float* beta   = (const float*)d_in[8];
    float* ws  = (float*)d_ws;
    float* out = (float*)d_out;

    k_att  <<<dim3(3, 64), 256, 0, stream>>>(x, Wqkv, bqkv, alphas, att0s, ws + WS_ATT);
    k_conv <<<dim3(32, 64), 256, 0, stream>>>(x, Wout, bout, ws + WS_ATT, out);
    k_stats<<<64,           256, 0, stream>>>(out, ws + WS_STATS);
    k_final<<<51200,        256, 0, stream>>>(ws + WS_STATS, x, gamma, beta, out);
}

// Round 5
// 1109.218 us; speedup vs baseline: 1.5607x; 1.5607x over previous
//
#include <hip/hip_runtime.h>
#include <hip/hip_bf16.h>

// Problem constants: N=64, C=64, T=128, V=25, H=3, DQ=32
// Inputs: float32. Output: float32 (compared under bf16-floored threshold).

#define WS_ATT   0         // 120000 floats: att accumulator, then final att
#define WS_STATS 120000    // 128 floats: per-channel sum, sumsq

// ---------------------------------------------------------------------------
// K1: att_raw[n,h,u,v] += sum over (c'=32, 16 frames) of q*k
// grid (8 t-slices, H=3, N=64) = 1536 blocks; 256 threads.
// xs staged transposed+padded: xs_s[j*68+c] so the hot loop reads contiguous c
// (ds_read_b128), writes hit rotating banks.
// ---------------------------------------------------------------------------
__global__ __launch_bounds__(256) void k_att(
    const float* __restrict__ x, const float* __restrict__ Wqkv,
    const float* __restrict__ bqkv, float* __restrict__ att_raw)
{
    __shared__ float wq_s[2048], wk_s[2048];   // [c'(32)][c(64)]
    __shared__ float bq_s[32], bk_s[32];
    __shared__ float pe_s[1600];               // [c][v]
    __shared__ float xs_s[3400];               // [j(50)][c(64)] pad 68
    __shared__ float q_s[1600], k_s[1600];     // [c'][j]

    const int tid = threadIdx.x;
    const int tblk = blockIdx.x;               // 16-frame slice
    const int h = blockIdx.y, n = blockIdx.z;

    for (int e = tid; e < 2048; e += 256) {
        int cp = e >> 6, c = e & 63;
        wq_s[e] = Wqkv[(h * 32 + cp) * 64 + c];
        wk_s[e] = Wqkv[(96 + h * 32 + cp) * 64 + c];
    }
    if (tid < 32) {
        bq_s[tid] = bqkv[h * 32 + tid];
        bk_s[tid] = bqkv[96 + h * 32 + tid];
    }
    for (int e = tid; e < 1600; e += 256) {
        int c = e / 25, v = e % 25;
        int i = c >> 1;
        float d = expf(-(float)(2 * i) * (9.210340371976184f / 64.0f));
        float a = (float)v * d;
        pe_s[e] = (c & 1) ? cosf(a) : sinf(a);
    }

    float racc[3] = {0.0f, 0.0f, 0.0f};   // owns p = tid, tid+256, tid+512

    for (int chunk = 0; chunk < 8; ++chunk) {
        const int t0 = tblk * 16 + chunk * 2;
        __syncthreads();   // protect xs_s / q_s / k_s from previous readers
        for (int e = tid; e < 3200; e += 256) {
            int c = e / 50, j = e % 50;
            int tl = j / 25, v = j % 25;
            xs_s[j * 68 + c] =
                x[((n * 64 + c) * 128 + t0 + tl) * 25 + v] + pe_s[c * 25 + v];
        }
        __syncthreads();
        for (int e = tid; e < 1600; e += 256) {
            int row = e / 50, j = e % 50;
            float aq = bq_s[row], ak = bk_s[row];
            const float* wqr = &wq_s[row * 64];
            const float* wkr = &wk_s[row * 64];
            const float* xr  = &xs_s[j * 68];
            #pragma unroll 8
            for (int c = 0; c < 64; ++c) {
                float xv = xr[c];
                aq = fmaf(wqr[c], xv, aq);
                ak = fmaf(wkr[c], xv, ak);
            }
            q_s[e] = aq; k_s[e] = ak;
        }
        __syncthreads();
        #pragma unroll
        for (int s = 0; s < 3; ++s) {
            int p = tid + s * 256;
            if (p < 625) {
                int u = p / 25, v = p % 25;
                float acc = racc[s];
                for (int cp = 0; cp < 32; ++cp) {
                    const float* qr = &q_s[cp * 50];
                    const float* kr = &k_s[cp * 50];
                    acc = fmaf(qr[u],      kr[v],      acc);
                    acc = fmaf(qr[25 + u], kr[25 + v], acc);
                }
                racc[s] = acc;
            }
        }
    }

    #pragma unroll
    for (int s = 0; s < 3; ++s) {
        int p = tid + s * 256;
        if (p < 625)
            atomicAdd(&att_raw[(n * 3 + h) * 625 + p], racc[s]);
    }
}

// ---------------------------------------------------------------------------
// K1b: att = tanh(att_raw/4096)*alpha[h] + att0[h,u,v]  (in place)
// ---------------------------------------------------------------------------
__global__ void k_attfin(float* __restrict__ att, const float* __restrict__ alphas,
                         const float* __restrict__ att0s)
{
    int idx = blockIdx.x * 256 + threadIdx.x;
    if (idx >= 64 * 3 * 625) return;
    int nh = idx / 625, p = idx % 625;
    int h = nh % 3;
    float a = att[idx];
    att[idx] = tanhf(a * (1.0f / 4096.0f)) * alphas[h] + att0s[h * 625 + p];
}

// ---------------------------------------------------------------------------
// K2: fused y = x . att  and  conv1x5 (+bias) -> fp32 into d_out (staging).
// grid (T/4=32, N=64); 256 threads; thread = (o=tid>>2, tl=tid&3).
// ---------------------------------------------------------------------------
__global__ __launch_bounds__(256) void k_conv(
    const float* __restrict__ x, const float* __restrict__ Wout,
    const float* __restrict__ bout, const float* __restrict__ att,
    float* __restrict__ out)
{
    __shared__ float x_s[6400];    // [c][t(4)*25+v]
    __shared__ float y_s[7424];    // [c][t][vv(29)] zero-padded halo
    __shared__ float att_s[625];

    const int tid = threadIdx.x;
    const int n = blockIdx.y;
    const int t0 = blockIdx.x * 4;
    const int o = tid >> 2, tl = tid & 3;

    for (int e = tid; e < 6400; e += 256) {
        int c = e / 100, r = e % 100;
        int t = r / 25, v = r % 25;
        x_s[e] = x[((n * 64 + c) * 128 + t0 + t) * 25 + v];   // raw x (no pe)
    }
    float acc[25];
    #pragma unroll
    for (int v = 0; v < 25; ++v) acc[v] = 0.0f;

    const float* attw = att + n * 3 * 625;
    for (int h = 0; h < 3; ++h) {
        __syncthreads();           // x_s ready (h=0) / previous y_s,att_s consumed
        for (int e = tid; e < 625; e += 256) att_s[e] = attw[h * 625 + e];
        __syncthreads();
        for (int e = tid; e < 7424; e += 256) {
            int c = e / 116, r = e % 116;
            int t = r / 29, vv = r % 29;
            float s = 0.0f;
            if (vv >= 2 && vv < 27) {
                int v = vv - 2;
                const float* xr = &x_s[c * 100 + t * 25];
                #pragma unroll
                for (int u = 0; u < 25; ++u) s = fmaf(xr[u], att_s[u * 25 + v], s);
            }
            y_s[e] = s;
        }
        __syncthreads();
        for (int c = 0; c < 64; ++c) {
            float yr[29];
            const float* ysrc = &y_s[c * 116 + tl * 29];
            #pragma unroll
            for (int i = 0; i < 29; ++i) yr[i] = ysrc[i];
            const float* wp = &Wout[(size_t)((o * 192) + h * 64 + c) * 5];
            float w0 = wp[0], w1 = wp[1], w2 = wp[2], w3 = wp[3], w4 = wp[4];
            #pragma unroll
            for (int v = 0; v < 25; ++v)
                acc[v] += w0 * yr[v] + w1 * yr[v + 1] + w2 * yr[v + 2]
                        + w3 * yr[v + 3] + w4 * yr[v + 4];
        }
    }
    const float bo = bout[o];
    float* outp = out + ((size_t)(n * 64 + o) * 128 + t0 + tl) * 25;
    #pragma unroll
    for (int v = 0; v < 25; ++v) outp[v] = acc[v] + bo;
}

// ---------------------------------------------------------------------------
// K3: per-channel sum/sumsq of conv output (fp32, staged in d_out).
// ---------------------------------------------------------------------------
__global__ __launch_bounds__(256) void k_stats(const float* __restrict__ conv,
                                               float* __restrict__ stats)
{
    const int o = blockIdx.x;
    const int tid = threadIdx.x;
    float s1 = 0.0f, s2 = 0.0f;
    for (int e = tid; e < 64 * 3200; e += 256) {
        int nn = e / 3200, i = e % 3200;
        float v = conv[(size_t)(nn * 64 + o) * 3200 + i];
        s1 += v; s2 = fmaf(v, v, s2);
    }
    for (int off = 32; off > 0; off >>= 1) {
        s1 += __shfl_down(s1, off);
        s2 += __shfl_down(s2, off);
    }
    __shared__ float r1[4], r2[4];
    int w = tid >> 6;
    if ((tid & 63) == 0) { r1[w] = s1; r2[w] = s2; }
    __syncthreads();
    if (tid == 0) {
        stats[o]      = r1[0] + r1[1] + r1[2] + r1[3];
        stats[64 + o] = r2[0] + r2[1] + r2[2] + r2[3];
    }
}

// ---------------------------------------------------------------------------
// K4: out = leaky_relu( BN(conv) + x ), in place over d_out (1 thread/elem).
// ---------------------------------------------------------------------------
__global__ void k_final(const float* __restrict__ stats, const float* __restrict__ x,
                        const float* __restrict__ gamma, const float* __restrict__ beta,
                        float* __restrict__ out)
{
    size_t idx = (size_t)blockIdx.x * 256 + threadIdx.x;
    if (idx >= (size_t)13107200) return;
    int o = (int)((idx / 3200) & 63);
    const float inv = 1.0f / 204800.0f;
    float m   = stats[o] * inv;
    float ex2 = stats[64 + o] * inv;
    float var = ex2 - m * m;
    float r = rsqrtf(var + 1e-5f);
    float v = out[idx];
    float val = (v - m) * r * gamma[o] + beta[o] + x[idx];
    val = fmaxf(val, 0.1f * val);
    out[idx] = val;
}

// ---------------------------------------------------------------------------
extern "C" void kernel_launch(void* const* d_in, const int* in_sizes, int n_in,
                              void* d_out, int out_size, void* d_ws, size_t ws_size,
                              hipStream_t stream)
{
    const float* x      = (const float*)d_in[0];
    const float* Wqkv   = (const float*)d_in[1];
    const float* bqkv   = (const float*)d_in[2];
    const float* alphas = (const float*)d_in[3];
    const float* att0s  = (const float*)d_in[4];
    const float* Wout   = (const float*)d_in[5];
    const float* bout   = (const float*)d_in[6];
    const float* gamma  = (const float*)d_in[7];
    const float* beta   = (const float*)d_in[8];
    float* ws  = (float*)d_ws;
    float* out = (float*)d_out;

    hipMemsetAsync(d_ws, 0, (size_t)120000 * sizeof(float), stream);

    k_att   <<<dim3(8, 3, 64), 256, 0, stream>>>(x, Wqkv, bqkv, ws + WS_ATT);
    k_attfin<<<(120000 + 255) / 256, 256, 0, stream>>>(ws + WS_ATT, alphas, att0s);
    k_conv  <<<dim3(32, 64),   256, 0, stream>>>(x, Wout, bout, ws + WS_ATT, out);
    k_stats <<<64,             256, 0, stream>>>(out, ws + WS_STATS);
    k_final <<<51200,          256, 0, stream>>>(ws + WS_STATS, x, gamma, beta, out);
}